// Round 8
// baseline (231.324 us; speedup 1.0000x reference)
//
#include <hip/hip_runtime.h>
#include <hip/hip_bf16.h>

#define NT 1024
#define TT 192
#define PBA 222     // bufA rows (L0/L2 output)
#define PBB 220     // bufB rows (L1/L3 output)
#define NB 16
#define T_ 16384
#define W_ 32
#define TW_ (T_ - W_)
#define SLOPE_C 0.22916666666666666f

// weight image layout (ushort offsets in workspace):
//   0      : W1 (2 planes x 8192, swizzled)
//   16384  : W2
//   32768  : W3
//   49152  : W4 (2 planes x 2048, rows 8..15 zeroed)
//   53248  : consts as float[1024] (see kW)
#define WIMG_W4   49152
#define WIMG_CST  53248
#define WIMG_USH  55296          // total ushorts (= 27648 floats)

typedef short v8s __attribute__((ext_vector_type(8)));
typedef float v4f __attribute__((ext_vector_type(4)));

__device__ __forceinline__ float rr(float v){ return v >= 0.f ? v : v * SLOPE_C; }
__device__ __forceinline__ ushort f2bs(float f){ __hip_bfloat16 h = __float2bfloat16(f); return *(ushort*)&h; }
__device__ __forceinline__ float bs2f(ushort u){ union{unsigned i; float f;} v; v.i = ((unsigned)u) << 16; return v.f; }

// Act row = 128 ushorts ([hi 64][lo 64]) = 16 granules of 8 ushorts (16 B).
// Physical granule = logical granule ^ (p & 15)  -> b128 reads bank-uniform.
__device__ __forceinline__ int agr(int p, int gi){ return p*128 + ((gi ^ (p & 15)) << 3); }
// Weight row = 64 ushorts = 8 granules; physical = logical ^ (wr & 7)
__device__ __forceinline__ int widx(int wr, int ci){
  return wr*64 + ((((ci >> 3) ^ (wr & 7)) << 3) | (ci & 7));
}

// ---------------- pre-kernel: build swizzled hi/lo weight image ----------------
__global__ __launch_bounds__(256) void kW(
    const float* __restrict__ cw1, const float* __restrict__ cw2,
    const float* __restrict__ cw3, const float* __restrict__ cw4,
    const float* __restrict__ cw0, const float* __restrict__ cb0,
    const float* __restrict__ cb1, const float* __restrict__ cb2,
    const float* __restrict__ cb3, const float* __restrict__ cb4,
    const float* __restrict__ mw0, const float* __restrict__ mb0,
    const float* __restrict__ mw1, const float* __restrict__ mb1,
    const float* __restrict__ mw2, const float* __restrict__ mb2,
    ushort* __restrict__ wimg)
{
  const int id = blockIdx.x*256 + threadIdx.x;
  if (id < 24576){                       // W1..W3: (64,64,2) each
    int l = id >> 13, e = id & 8191;
    const float* src = (l == 0) ? cw1 : ((l == 1) ? cw2 : cw3);
    int c = e >> 7, rem = e & 127, ci = rem >> 1, k = rem & 1;
    float v = src[e];
    ushort h = f2bs(v), lo = f2bs(v - bs2f(h));
    int ix = widx(k*64 + c, ci);
    wimg[l*16384 + ix] = h;
    wimg[l*16384 + 8192 + ix] = lo;
  } else if (id < 25600){                // W4: (8,64,2), M rows 0..7
    int e = id - 24576;
    int c = e >> 7, rem = e & 127, ci = rem >> 1, k = rem & 1;
    float v = cw4[e];
    ushort h = f2bs(v), lo = f2bs(v - bs2f(h));
    int ix = widx(k*16 + c, ci);
    wimg[WIMG_W4 + ix] = h;
    wimg[WIMG_W4 + 2048 + ix] = lo;
  } else if (id < 27648){                // W4: zero rows m=8..15, both planes
    int e = id - 25600;
    int pl = e >> 10, rem = e & 1023, k = rem >> 9, r2 = rem & 511;
    int m = 8 + (r2 >> 6), ci = r2 & 63;
    wimg[WIMG_W4 + pl*2048 + widx(k*16 + m, ci)] = 0;
  } else if (id < 28672){                // consts (float[1024])
    int e = id - 27648;
    float v = 0.f;
    if      (e < 256) v = mw0[e];
    else if (e < 512) v = mw1[e - 256];
    else if (e < 528) v = mw2[e - 512];
    else if (e < 544) v = mb0[e - 528];
    else if (e < 560) v = mb1[e - 544];
    else if (e < 561) v = mb2[0];
    else if (e >= 576 && e < 584) v = cb4[e - 576];
    else if (e >= 592 && e < 720) v = cw0[e - 592];
    else if (e >= 720 && e < 784) v = cb0[e - 720];
    else if (e >= 784 && e < 848) v = cb1[e - 784];
    else if (e >= 848 && e < 912) v = cb2[e - 848];
    else if (e >= 912 && e < 976) v = cb3[e - 912];
    ((float*)(wimg + WIMG_CST))[e] = v;
  }
}

// 64->64 dilated conv on MFMA with hi/lo bf16 (3-term). Waves 0..6, 32 pos each.
template<int D, int NSRC, int NDST>
__device__ __forceinline__ void mfma_layer(const ushort* __restrict__ src,
    ushort* __restrict__ dst, const ushort* __restrict__ wlds,
    const float* __restrict__ cbias, int tid)
{
  const int wave = tid >> 6;
  if (wave >= 7) return;
  const int lane = tid & 63;
  const int n = lane & 15, quad = lane >> 4;
  const int p0 = wave * 32;

  v4f acc[8];
  const v4f vz = {0.f, 0.f, 0.f, 0.f};
#pragma unroll
  for (int i = 0; i < 8; ++i) acc[i] = vz;

#pragma unroll
  for (int tap = 0; tap < 2; ++tap){
#pragma unroll
    for (int kb = 0; kb < 2; ++kb){
      const int kg = kb*4 + quad;                // logical k-granule 0..7
      v8s wh[4], wl[4], ah[2], al[2];
#pragma unroll
      for (int mt = 0; mt < 4; ++mt){
        int wr = tap*64 + mt*16 + n;
        int base = wr*64 + ((kg ^ (wr & 7)) << 3);
        wh[mt] = *(const v8s*)(wlds + base);
        wl[mt] = *(const v8s*)(wlds + 8192 + base);
      }
#pragma unroll
      for (int nt = 0; nt < 2; ++nt){
        int p = p0 + nt*16 + n + tap*D;
        if (p >= NSRC) p = NSRC - 1;             // clamp: invalid outputs only
        ah[nt] = *(const v8s*)(src + agr(p, kg));
        al[nt] = *(const v8s*)(src + agr(p, 8 + kg));
      }
#pragma unroll
      for (int nt = 0; nt < 2; ++nt)
#pragma unroll
        for (int mt = 0; mt < 4; ++mt){
          v4f a = acc[nt*4 + mt];
          a = __builtin_amdgcn_mfma_f32_16x16x32_bf16(wh[mt], ah[nt], a, 0, 0, 0);
          a = __builtin_amdgcn_mfma_f32_16x16x32_bf16(wh[mt], al[nt], a, 0, 0, 0);
          a = __builtin_amdgcn_mfma_f32_16x16x32_bf16(wl[mt], ah[nt], a, 0, 0, 0);
          acc[nt*4 + mt] = a;
        }
    }
  }

  // epilogue: D col=lane&15 (pos), row=quad*4+r (cout); store hi/lo pairs
#pragma unroll
  for (int nt = 0; nt < 2; ++nt){
    int p = p0 + nt*16 + n;
    if (p < NDST){
#pragma unroll
      for (int mt = 0; mt < 4; ++mt){
#pragma unroll
        for (int r = 0; r < 4; r += 2){
          int c = mt*16 + quad*4 + r;
          float y0 = rr(acc[nt*4 + mt][r]     + cbias[c]);
          float y1 = rr(acc[nt*4 + mt][r + 1] + cbias[c + 1]);
          ushort h0 = f2bs(y0), h1 = f2bs(y1);
          ushort l0 = f2bs(y0 - bs2f(h0)), l1 = f2bs(y1 - bs2f(h1));
          int gh = agr(p, c >> 3)       + (c & 7);
          int gl = agr(p, 8 + (c >> 3)) + (c & 7);
          *(unsigned*)(dst + gh) = (unsigned)h0 | ((unsigned)h1 << 16);
          *(unsigned*)(dst + gl) = (unsigned)l0 | ((unsigned)l1 << 16);
        }
      }
    }
  }
}

template<bool GZT>
__global__ __launch_bounds__(NT, 4) void kA(
    const float* __restrict__ x, const float* __restrict__ gum,
    const ushort* __restrict__ wimg,
    float* __restrict__ ws_mus, float* __restrict__ out_gz,
    float* __restrict__ gzt)
{
  __shared__ __align__(16) ushort bufA[PBA*128];   // 56,832 B
  __shared__ __align__(16) ushort bufB[PBB*128];   // 56,320 B
  __shared__ __align__(16) ushort wlds[16384];     // 32,768 B (current layer)
  __shared__ __align__(16) ushort w4lds[4096];     //  8,192 B
  __shared__ __align__(16) float  cstl[1024];      //  4,096 B  -> 158,208 B total

  float* xbuf = (float*)bufB;            // alias: dead before L1 writes bufB

  const int tile = blockIdx.x, b = blockIdx.y;
  const int t0 = tile * TT;
  const int core = (T_ - t0 < TT) ? (T_ - t0) : TT;
  const int tid = threadIdx.x;

  // Phase A: stage x, W1, W4, consts (all linear copies of the pre-built image)
  const int nx = core + 31;
  for (int i = tid; i < nx; i += NT){
    int g = t0 + i;
    xbuf[i] = (g >= 31) ? x[(size_t)b*T_ + g - 31] : 0.f;
  }
  for (int i = tid; i < 2048; i += NT)
    *(v8s*)(wlds + i*8) = *(const v8s*)(wimg + i*8);
  for (int i = tid; i < 512; i += NT)
    *(v8s*)(w4lds + i*8) = *(const v8s*)(wimg + WIMG_W4 + i*8);
  for (int i = tid; i < 512; i += NT)
    ((float2*)cstl)[i] = ((const float2*)(wimg + WIMG_CST))[i];
  __syncthreads();

  // Layer0 (1->64, d=1) VALU, all 1024 threads
  {
    const int n0 = core + 30;
    for (int i = tid; i < PBA*64; i += NT){
      int p = i >> 6, c = i & 63;
      float y = 0.f;
      if (p < n0) y = rr(cstl[720 + c] + cstl[592 + 2*c]*xbuf[p] + cstl[593 + 2*c]*xbuf[p + 1]);
      ushort h = f2bs(y); ushort lo = f2bs(y - bs2f(h));
      bufA[agr(p, c >> 3)       + (c & 7)] = h;
      bufA[agr(p, 8 + (c >> 3)) + (c & 7)] = lo;
    }
  }
  __syncthreads();

  mfma_layer<2, PBA, PBB>(bufA, bufB, wlds, cstl + 784, tid);   // layer1
  __syncthreads();
  for (int i = tid; i < 2048; i += NT)                          // stage W2
    *(v8s*)(wlds + i*8) = *(const v8s*)(wimg + 16384 + i*8);
  __syncthreads();
  mfma_layer<4, PBB, PBA>(bufB, bufA, wlds, cstl + 848, tid);   // layer2
  __syncthreads();
  for (int i = tid; i < 2048; i += NT)                          // stage W3
    *(v8s*)(wlds + i*8) = *(const v8s*)(wimg + 32768 + i*8);
  __syncthreads();
  mfma_layer<8, PBA, PBB>(bufA, bufB, wlds, cstl + 912, tid);   // layer3 -> bufB
  __syncthreads();

  // Layer4 (64->8, d=16) on MFMA: M=16 tile, rows 8..15 zero
  float* h4s = (float*)bufA;             // [8][TT] fp32 (L2 data dead)
  {
    const int wave = tid >> 6;
    if (wave < 7){
      const int lane = tid & 63;
      const int n = lane & 15, quad = lane >> 4;
      const int p0 = wave * 32;
      v4f acc2[2];
      const v4f vz = {0.f, 0.f, 0.f, 0.f};
      acc2[0] = vz; acc2[1] = vz;
#pragma unroll
      for (int tap = 0; tap < 2; ++tap){
#pragma unroll
        for (int kb = 0; kb < 2; ++kb){
          const int kg = kb*4 + quad;
          int wr = tap*16 + n;
          int base = wr*64 + ((kg ^ (wr & 7)) << 3);
          v8s wh = *(const v8s*)(w4lds + base);
          v8s wl = *(const v8s*)(w4lds + 2048 + base);
#pragma unroll
          for (int nt = 0; nt < 2; ++nt){
            int p = p0 + nt*16 + n + tap*16;
            if (p >= PBB) p = PBB - 1;
            v8s ah = *(const v8s*)(bufB + agr(p, kg));
            v8s al = *(const v8s*)(bufB + agr(p, 8 + kg));
            v4f a = acc2[nt];
            a = __builtin_amdgcn_mfma_f32_16x16x32_bf16(wh, ah, a, 0, 0, 0);
            a = __builtin_amdgcn_mfma_f32_16x16x32_bf16(wh, al, a, 0, 0, 0);
            a = __builtin_amdgcn_mfma_f32_16x16x32_bf16(wl, ah, a, 0, 0, 0);
            acc2[nt] = a;
          }
        }
      }
#pragma unroll
      for (int nt = 0; nt < 2; ++nt){
        int p = p0 + nt*16 + n;
        if (p < core && quad < 2){
#pragma unroll
          for (int r = 0; r < 4; ++r){
            int c = quad*4 + r;
            h4s[c*TT + p] = rr(acc2[nt][r] + cstl[576 + c]);
          }
        }
      }
    }
  }
  __syncthreads();

  // Phase J: softmax + pointwise MLP per position
  if (tid < core){
    const int t = t0 + tid;
    float l[8];
#pragma unroll
    for (int r = 0; r < 8; ++r) l[r] = h4s[r*TT + tid];
    float gv[8];
    *(float4*)&gv[0] = *(const float4*)(gum + (size_t)(b*T_ + t)*8);
    *(float4*)&gv[4] = *(const float4*)(gum + (size_t)(b*T_ + t)*8 + 4);
    float s[8], mx = -1e30f;
#pragma unroll
    for (int r = 0; r < 8; ++r){ s[r] = (l[r] + gv[r]) * 10.0f; mx = fmaxf(mx, s[r]); }
    float e[8], sum = 0.f;
#pragma unroll
    for (int r = 0; r < 8; ++r){ e[r] = __expf(s[r] - mx); sum += e[r]; }
    float inv = 1.0f / sum;
    float z[8];
#pragma unroll
    for (int r = 0; r < 8; ++r){
      z[r] = e[r] * inv;
      out_gz[(size_t)(b*8 + r)*T_ + t] = z[r];
    }
    if (GZT){
      *(float4*)(gzt + (size_t)(b*T_ + t)*8)     = make_float4(z[0], z[1], z[2], z[3]);
      *(float4*)(gzt + (size_t)(b*T_ + t)*8 + 4) = make_float4(z[4], z[5], z[6], z[7]);
    }
    float m0[16];
#pragma unroll
    for (int o = 0; o < 16; ++o){
      float a = cstl[528 + o];
#pragma unroll
      for (int i = 0; i < 8; ++i) a += cstl[o*16 + i] * z[i];
#pragma unroll
      for (int i = 0; i < 8; ++i) a += cstl[o*16 + 8 + i] * l[i];
      m0[o] = rr(a);
    }
    float m1[16];
#pragma unroll
    for (int o = 0; o < 16; ++o){
      float a = cstl[544 + o];
#pragma unroll
      for (int i = 0; i < 16; ++i) a += cstl[256 + o*16 + i] * m0[i];
      m1[o] = rr(a);
    }
    float mu = cstl[560];
#pragma unroll
    for (int i = 0; i < 16; ++i) mu += cstl[512 + i] * m1[i];
    ws_mus[(size_t)b*T_ + t] = mu;
  }
}

template<bool GZT>
__global__ __launch_bounds__(256) void kB(
    const float* __restrict__ x, const float* __restrict__ fish,
    const float* __restrict__ sct, const float* __restrict__ ws_mus,
    const float* __restrict__ gz, float* __restrict__ out0)
{
  __shared__ float xm[288], mm[288], fs[256], sc[8];
  const int b = blockIdx.y;
  const int s = blockIdx.x * 256;
  const int tid = threadIdx.x;
  for (int i = tid; i < 288; i += 256){
    int g = s + i;
    bool ok = g < T_;
    xm[i] = ok ? x[(size_t)b*T_ + g] : 0.f;
    mm[i] = ok ? ws_mus[(size_t)b*T_ + g] : 0.f;
  }
  fs[tid] = fish[tid];
  if (tid < 8) sc[tid] = sct[tid];
  __syncthreads();
  const int tp = s + tid;
  if (tp < TW_){
    const int t = W_ + tp;
    float z[8];
    if (GZT){
      *(float4*)&z[0] = *(const float4*)(gz + (size_t)(b*T_ + t)*8);
      *(float4*)&z[4] = *(const float4*)(gz + (size_t)(b*T_ + t)*8 + 4);
    } else {
#pragma unroll
      for (int r = 0; r < 8; ++r) z[r] = gz[(size_t)(b*8 + r)*T_ + t];
    }
    float cv = 0.f;
#pragma unroll
    for (int r = 0; r < 8; ++r) cv += sc[r] * z[r];
    cv *= cv;
    float acc = 0.f;
#pragma unroll 4
    for (int w = 0; w < 32; ++w){
      float fj = 0.f;
#pragma unroll
      for (int r = 0; r < 8; ++r) fj += z[r] * fs[r*32 + w];
      acc += fj * (xm[tid + w] - mm[tid + w]);
    }
    out0[(size_t)b*TW_ + tp] = mm[tid + 32] - cv * acc;
  }
}

extern "C" void kernel_launch(void* const* d_in, const int* in_sizes, int n_in,
                              void* d_out, int out_size, void* d_ws, size_t ws_size,
                              hipStream_t stream)
{
  const float* x   = (const float*)d_in[0];
  const float* cw0 = (const float*)d_in[1];
  const float* cb0 = (const float*)d_in[2];
  const float* cw1 = (const float*)d_in[3];
  const float* cb1 = (const float*)d_in[4];
  const float* cw2 = (const float*)d_in[5];
  const float* cb2 = (const float*)d_in[6];
  const float* cw3 = (const float*)d_in[7];
  const float* cb3 = (const float*)d_in[8];
  const float* cw4 = (const float*)d_in[9];
  const float* cb4 = (const float*)d_in[10];
  const float* mw0 = (const float*)d_in[11];
  const float* mb0 = (const float*)d_in[12];
  const float* mw1 = (const float*)d_in[13];
  const float* mb1 = (const float*)d_in[14];
  const float* mw2 = (const float*)d_in[15];
  const float* mb2 = (const float*)d_in[16];
  const float* sct = (const float*)d_in[17];
  const float* fish= (const float*)d_in[18];
  const float* gum = (const float*)d_in[19];

  float* out0   = (float*)d_out;               // _mus: (16, 16352)
  float* out_gz = out0 + NB*TW_;               // gen_z: (16, 8, 16384)
  float* ws_mus = (float*)d_ws;                // [0, 262144): fp32 mus
  ushort* wimg  = (ushort*)(ws_mus + (size_t)NB*T_);   // 27648 floats
  float* gzt    = ws_mus + (size_t)NB*T_ + WIMG_USH/2; // transposed gen_z (b,t,r)

  const size_t need_gzt = ((size_t)NB*T_ + WIMG_USH/2 + (size_t)8*NB*T_) * sizeof(float);
  const bool use_t = ws_size >= need_gzt;

  kW<<<112, 256, 0, stream>>>(cw1, cw2, cw3, cw4, cw0, cb0, cb1, cb2, cb3, cb4,
                              mw0, mb0, mw1, mb1, mw2, mb2, wimg);

  dim3 gA((T_ + TT - 1) / TT, NB);             // (86, 16)
  dim3 gB((TW_ + 255) / 256, NB);              // (64, 16)
  if (use_t){
    kA<true><<<gA, NT, 0, stream>>>(x, gum, wimg, ws_mus, out_gz, gzt);
    kB<true><<<gB, 256, 0, stream>>>(x, fish, sct, ws_mus, gzt, out0);
  } else {
    kA<false><<<gA, NT, 0, stream>>>(x, gum, wimg, ws_mus, out_gz, gzt);
    kB<false><<<gB, 256, 0, stream>>>(x, fish, sct, ws_mus, out_gz, out0);
  }
}